// Round 10
// baseline (287.257 us; speedup 1.0000x reference)
//
#include <hip/hip_runtime.h>
#include <stdint.h>

#define L2E 1.44269504088896f

static __device__ __forceinline__ float wsum(float v) {
    #pragma unroll
    for (int m = 1; m < 64; m <<= 1) v += __shfl_xor(v, m, 64);
    return v;
}
static __device__ __forceinline__ float sigm(float x) {
    return 1.0f / (1.0f + __builtin_amdgcn_exp2f(-x * L2E));
}
static __device__ __forceinline__ float tanh_(float x) {
    const float ax = fabsf(x);
    const float t = __builtin_amdgcn_exp2f(-2.0f * ax * L2E);
    const float r = (1.0f - t) / (1.0f + t);
    return (x < 0.f) ? -r : r;
}

// DPP helper: returns neighbor's value per compile-time ctrl (VALU-rate).
template <int CTRL>
static __device__ __forceinline__ float dppterm(float v) {
    return __int_as_float(__builtin_amdgcn_update_dpp(
        0, __float_as_int(v), CTRL, 0xF, 0xF, true));
}
// Butterfly sum over 8 contiguous lanes (chunk = lane&7). All adds
// commutative -> bitwise-identical result in all 8 lanes.
static __device__ __forceinline__ float red8(float v) {
    v += dppterm<0xB1>(v);    // quad_perm(1,0,3,2)  = xor1
    v += dppterm<0x4E>(v);    // quad_perm(2,3,0,1)  = xor2
    v += dppterm<0x141>(v);   // row_half_mirror     = xor7 (quads merged)
    return v;
}

// ---------------------------------------------------------------------------
// init: fused weight transpose (wihT/whhT/WkT) + slot broadcast + iter-0
// gkq/aux. grid 112 x 256. (R1-verbatim)
// ---------------------------------------------------------------------------
__global__ __launch_bounds__(256) void init_kernel(
    const float* __restrict__ s0,
    const float* __restrict__ lsg, const float* __restrict__ lsb,
    const float* __restrict__ Wq,  const float* __restrict__ Wk,
    const float* __restrict__ lig, const float* __restrict__ lib,
    const float* __restrict__ wih, const float* __restrict__ whh,
    float* __restrict__ slots, float* __restrict__ gkq, float* __restrict__ aux,
    float* __restrict__ wihT, float* __restrict__ whhT, float* __restrict__ WkT)
{
    __shared__ float wkT[4096];
    __shared__ float scr[4][64];
    const int tid = threadIdx.x, lane = tid & 63, wv = tid >> 6;
    const int idx = blockIdx.x * 256 + tid;

    if (idx < 12288) {
        const int i = idx / 192, j = idx - i * 192;
        wihT[idx] = wih[j * 64 + i];
    } else if (idx < 24576) {
        const int o = idx - 12288;
        const int i = o / 192, j = o - i * 192;
        whhT[o] = whh[j * 64 + i];
    } else {
        const int o = idx - 24576;
        const int p = o >> 6, d = o & 63;
        WkT[o] = Wk[d * 64 + p];
    }

    const int r = blockIdx.x * 4 + wv;          // 0..447
    const int s = r % 7;
    #pragma unroll
    for (int i = tid; i < 4096; i += 256) {
        const int d = i >> 6, p = i & 63;
        wkT[p * 64 + d] = Wk[i];
    }
    const float h = s0[s * 64 + lane];
    slots[r * 64 + lane] = h;
    __syncthreads();

    const float mean = wsum(h) * (1.0f / 64.0f);
    const float d = h - mean;
    const float var = wsum(d * d) * (1.0f / 64.0f);
    const float rs = rsqrtf(var + 1e-5f);
    const float sn = d * rs * lsg[lane] + lsb[lane];
    scr[wv][lane] = sn;
    __syncthreads();
    float q = 0.f;
    #pragma unroll 8
    for (int i = 0; i < 64; ++i) q = fmaf(scr[wv][i], Wq[i * 64 + lane], q);
    q *= 0.125f;
    __syncthreads();
    scr[wv][lane] = q;
    __syncthreads();
    float kq = 0.f;
    #pragma unroll 8
    for (int p = 0; p < 64; ++p) kq = fmaf(wkT[p * 64 + lane], scr[wv][p], kq);
    const float bk = wsum(lib[lane] * kq);
    const float gk = lig[lane] * kq;
    const float g1 = wsum(gk);
    gkq[r * 64 + lane] = gk;
    if (lane == 0) { aux[r * 2] = g1; aux[r * 2 + 1] = bk; }
}

// ---------------------------------------------------------------------------
// attn v5 (R9-verbatim, best-known): async global_load_lds staging, counted
// vmcnt, double-buffered per-wave LDS tiles, R1 math. grid 1024 x 256.
// This round: dispatched TWICE per iteration (second writes inert Ypart2)
// to solve for attn duration: a = (T_R10 - T_R9) / 3.
// ---------------------------------------------------------------------------
#define PROC(A0, A1)                                                         \
    do {                                                                     \
        const float xv[8] = {A0.x, A0.y, A0.z, A0.w, A1.x, A1.y, A1.z, A1.w};\
        float sum = 0.f, ss = 0.f;                                           \
        _Pragma("unroll")                                                    \
        for (int j = 0; j < 8; ++j) {                                        \
            sum += xv[j]; ss = fmaf(xv[j], xv[j], ss);                       \
        }                                                                    \
        float acc[7];                                                        \
        _Pragma("unroll")                                                    \
        for (int s = 0; s < 7; ++s) {                                        \
            float a = 0.f;                                                   \
            _Pragma("unroll")                                                \
            for (int j = 0; j < 8; ++j) a = fmaf(xv[j], gk[s][j], a);        \
            acc[s] = a;                                                      \
        }                                                                    \
        sum = red8(sum);                                                     \
        ss  = red8(ss);                                                      \
        _Pragma("unroll")                                                    \
        for (int s = 0; s < 7; ++s) acc[s] = red8(acc[s]);                   \
        const float m   = sum * (1.0f / 64.0f);                              \
        const float var = ss * (1.0f / 64.0f) - m * m;                       \
        const float rs  = rsqrtf(var + 1e-5f);                               \
        const float rsm = rs * m;                                            \
        float t[7];                                                          \
        _Pragma("unroll")                                                    \
        for (int s = 0; s < 7; ++s)                                          \
            t[s] = fmaf(rs, acc[s], fmaf(-rsm, g1[s], bk[s]));               \
        float mx = t[0];                                                     \
        _Pragma("unroll")                                                    \
        for (int s = 1; s < 7; ++s) mx = fmaxf(mx, t[s]);                    \
        float e[7], se = 0.f;                                                \
        _Pragma("unroll")                                                    \
        for (int s = 0; s < 7; ++s) {                                        \
            e[s] = __builtin_amdgcn_exp2f((t[s] - mx) * L2E);                \
            se += e[s];                                                      \
        }                                                                    \
        const float inv = 1.0f / se;                                         \
        _Pragma("unroll")                                                    \
        for (int s = 0; s < 7; ++s) {                                        \
            const float w = fmaf(e[s], inv, 1e-8f);                          \
            cacc[s] += w;                                                    \
            const float wrs = w * rs;                                        \
            _Pragma("unroll")                                                \
            for (int j = 0; j < 8; ++j)                                      \
                Yacc[s][j] = fmaf(wrs, xv[j], Yacc[s][j]);                   \
        }                                                                    \
    } while (0)

#define STAGE(G, BUF)                                                        \
    do {                                                                     \
        const char* gs_ = (const char*)xw + (G) * 2048 + lane * 16;          \
        char* ls_ = (char*)&xbuf[wv][BUF][0][0];                             \
        __builtin_amdgcn_global_load_lds(                                    \
            (const __attribute__((address_space(1))) unsigned int*)gs_,      \
            (__attribute__((address_space(3))) unsigned int*)ls_, 16, 0, 0); \
        __builtin_amdgcn_global_load_lds(                                    \
            (const __attribute__((address_space(1))) unsigned int*)(gs_ + 1024), \
            (__attribute__((address_space(3))) unsigned int*)(ls_ + 1024),   \
            16, 0, 0);                                                       \
    } while (0)

#define WAITV(N)                                                             \
    do {                                                                     \
        asm volatile("s_waitcnt vmcnt(" #N ")" ::: "memory");                \
        __builtin_amdgcn_sched_barrier(0);                                   \
    } while (0)

#define PROCL(BUF)                                                           \
    do {                                                                     \
        const float4 A0_ = *(const float4*)&xbuf[wv][BUF][rsl][ck * 8];      \
        const float4 A1_ = *(const float4*)&xbuf[wv][BUF][rsl][ck * 8 + 4];  \
        PROC(A0_, A1_);                                                      \
    } while (0)

__global__ __launch_bounds__(256, 2) void attn_kernel(
    const float* __restrict__ x,
    const float* __restrict__ gkq, const float* __restrict__ aux,
    float* __restrict__ Ypart)
{
    __shared__ float ybuf[16][460];             // 29.4 KB
    __shared__ float xbuf[4][2][8][64];         // 16 KB
    const int tid = threadIdx.x, lane = tid & 63, wv = tid >> 6;
    const int b = blockIdx.x >> 4, chunk16 = blockIdx.x & 15;
    const int ck  = lane & 7;                   // dim-chunk 0..7
    const int rsl = lane >> 3;                  // row-slot 0..7

    float gk[7][8];
    {
        const float4* gp = (const float4*)(gkq + b * 448 + ck * 8);
        #pragma unroll
        for (int s = 0; s < 7; ++s) {
            const float4 u0 = gp[s * 16], u1 = gp[s * 16 + 1];
            gk[s][0] = u0.x; gk[s][1] = u0.y; gk[s][2] = u0.z; gk[s][3] = u0.w;
            gk[s][4] = u1.x; gk[s][5] = u1.y; gk[s][6] = u1.z; gk[s][7] = u1.w;
        }
    }
    const float* ab = aux + b * 14;
    float g1[7], bk[7];
    #pragma unroll
    for (int s = 0; s < 7; ++s) { g1[s] = ab[2 * s]; bk[s] = ab[2 * s + 1]; }

    float Yacc[7][8];
    #pragma unroll
    for (int s = 0; s < 7; ++s)
        #pragma unroll
        for (int j = 0; j < 8; ++j) Yacc[s][j] = 0.f;
    float cacc[7] = {0.f, 0.f, 0.f, 0.f, 0.f, 0.f, 0.f};

    const float* xw = x + (((long)b * 4096) + chunk16 * 256 + wv * 64) * 64;

    asm volatile("s_waitcnt vmcnt(0)" ::: "memory");
    __builtin_amdgcn_sched_barrier(0);

    STAGE(0, 0);
    STAGE(1, 1); WAITV(2); PROCL(0);
    STAGE(2, 0); WAITV(2); PROCL(1);
    STAGE(3, 1); WAITV(2); PROCL(0);
    STAGE(4, 0); WAITV(2); PROCL(1);
    STAGE(5, 1); WAITV(2); PROCL(0);
    STAGE(6, 0); WAITV(2); PROCL(1);
    STAGE(7, 1); WAITV(2); PROCL(0);
                 WAITV(0); PROCL(1);

    #pragma unroll
    for (int s = 0; s < 7; ++s) {
        #pragma unroll
        for (int j = 0; j < 8; ++j)
            Yacc[s][j] += dppterm<0x128>(Yacc[s][j]);
        cacc[s] += dppterm<0x128>(cacc[s]);
    }
    if (((lane >> 3) & 1) == 0) {
        const int sub = lane >> 4;              // 0..3
        float* yb = &ybuf[wv * 4 + sub][ck * 8];
        #pragma unroll
        for (int s = 0; s < 7; ++s) {
            #pragma unroll
            for (int j = 0; j < 8; ++j) yb[s * 64 + j] = Yacc[s][j];
        }
        if (ck == 0) {
            #pragma unroll
            for (int s = 0; s < 7; ++s)
                ybuf[wv * 4 + sub][448 + s] = cacc[s];
        }
    }
    __syncthreads();
    for (int i = tid; i < 455; i += 256) {
        float v = 0.f;
        #pragma unroll
        for (int p = 0; p < 16; ++p) v += ybuf[p][i];
        Ypart[((long)b * 16 + chunk16) * 456 + i] = v;
    }
}

// ---------------------------------------------------------------------------
// update v2 (R1-verbatim): one block (256 thr) per (b,s) row. grid 448.
// ---------------------------------------------------------------------------
__global__ __launch_bounds__(256) void update_kernel(
    const float* __restrict__ Ypart, float* __restrict__ slots,
    const float* __restrict__ Wv,
    const float* __restrict__ wihT, const float* __restrict__ whhT,
    const float* __restrict__ bih,  const float* __restrict__ bhh,
    const float* __restrict__ w1,   const float* __restrict__ b1,
    const float* __restrict__ w2,   const float* __restrict__ b2,
    const float* __restrict__ lsg,  const float* __restrict__ lsb,
    const float* __restrict__ Wq,   const float* __restrict__ WkT,
    const float* __restrict__ lig,  const float* __restrict__ lib,
    float* __restrict__ gkq, float* __restrict__ aux,
    float* __restrict__ out, int last)
{
    __shared__ float red[4][64];
    __shared__ float c16[16];
    __shared__ float ash[64];
    __shared__ float ush[64];
    __shared__ float hsh[64];
    __shared__ float gish[192], ghsh[192];
    __shared__ float hnsh[64];
    __shared__ float mbsh[128];
    __shared__ float qsh[64];
    const int tid = threadIdx.x, lane = tid & 63, wv = tid >> 6;
    const int r = blockIdx.x;                   // 0..447
    const int b = r / 7, s = r - b * 7;
    const float* Yb = Ypart + (long)b * 16 * 456;

    float yp = 0.f;
    #pragma unroll
    for (int c = 0; c < 4; ++c)
        yp += Yb[(wv * 4 + c) * 456 + s * 64 + lane];
    red[wv][lane] = yp;
    if (tid < 16) c16[tid] = Yb[tid * 456 + 448 + s];
    if (tid >= 64 && tid < 128) hsh[tid - 64] = slots[r * 64 + (tid - 64)];
    __syncthreads();

    if (tid < 64) {                             // wave 0
        const float Yd = red[0][lane] + red[1][lane] + red[2][lane] + red[3][lane];
        float C = 0.f;
        #pragma unroll
        for (int c = 0; c < 16; ++c) C += c16[c];
        const float Z = wsum(Yd) * (1.0f / 64.0f);   // Z = sum_d Y / 64
        ash[lane] = (lig[lane] * (Yd - Z) + lib[lane] * C) / C;
    }
    __syncthreads();

    float up = 0.f;
    #pragma unroll
    for (int i = 0; i < 16; ++i) {
        const int ii = wv * 16 + i;
        up = fmaf(ash[ii], Wv[ii * 64 + lane], up);
    }
    red[wv][lane] = up;
    __syncthreads();
    if (tid < 64) ush[lane] = red[0][lane] + red[1][lane] + red[2][lane] + red[3][lane];
    __syncthreads();

    if (tid < 192) {
        float a1 = bih[tid], a2 = bhh[tid];
        #pragma unroll 8
        for (int i = 0; i < 64; ++i) {
            a1 = fmaf(ush[i], wihT[i * 192 + tid], a1);
            a2 = fmaf(hsh[i], whhT[i * 192 + tid], a2);
        }
        gish[tid] = a1; ghsh[tid] = a2;
    }
    __syncthreads();
    if (tid < 64) {
        const float rr = sigm(gish[tid] + ghsh[tid]);
        const float zz = sigm(gish[64 + tid] + ghsh[64 + tid]);
        const float nn = tanh_(gish[128 + tid] + rr * ghsh[128 + tid]);
        hnsh[tid] = (1.f - zz) * nn + zz * hsh[tid];
    }
    __syncthreads();

    if (tid < 128) {
        float m = b1[tid];
        #pragma unroll 8
        for (int i = 0; i < 64; ++i) m = fmaf(hnsh[i], w1[i * 128 + tid], m);
        mbsh[tid] = fmaxf(m, 0.f);
    }
    __syncthreads();

    if (tid < 64) {
        float o = b2[tid];
        #pragma unroll 8
        for (int t = 0; t < 128; ++t) o = fmaf(mbsh[t], w2[t * 64 + tid], o);
        const float snv = hnsh[tid] + o;
        slots[r * 64 + tid] = snv;
        if (last) {
            out[r * 64 + tid] = snv;
        } else {
            const float mean = wsum(snv) * (1.0f / 64.0f);
            const float d = snv - mean;
            const float var = wsum(d * d) * (1.0f / 64.0f);
            const float rs = rsqrtf(var + 1e-5f);
            const float sn = d * rs * lsg[tid] + lsb[tid];
            ash[tid] = sn;                       // wave0-internal reuse
            float q = 0.f;
            #pragma unroll 8
            for (int i = 0; i < 64; ++i) q = fmaf(ash[i], Wq[i * 64 + tid], q);
            qsh[tid] = q * 0.125f;
            float kq = 0.f;
            #pragma unroll 8
            for (int p = 0; p < 64; ++p) kq = fmaf(WkT[p * 64 + tid], qsh[p], kq);
            const float bk = wsum(lib[tid] * kq);
            const float gk = lig[tid] * kq;
            const float g1 = wsum(gk);
            gkq[r * 64 + tid] = gk;
            if (tid == 0) { aux[r * 2] = g1; aux[r * 2 + 1] = bk; }
        }
    }
}

// ---------------------------------------------------------------------------
extern "C" void kernel_launch(void* const* d_in, const int* in_sizes, int n_in,
                              void* d_out, int out_size, void* d_ws, size_t ws_size,
                              hipStream_t stream)
{
    const float* x   = (const float*)d_in[0];
    const float* lig = (const float*)d_in[1];
    const float* lib = (const float*)d_in[2];
    const float* lsg = (const float*)d_in[3];
    const float* lsb = (const float*)d_in[4];
    const float* s0  = (const float*)d_in[5];
    const float* Wk  = (const float*)d_in[6];
    const float* Wv  = (const float*)d_in[7];
    const float* Wq  = (const float*)d_in[8];
    const float* wih = (const float*)d_in[9];
    const float* whh = (const float*)d_in[10];
    const float* bih = (const float*)d_in[11];
    const float* bhh = (const float*)d_in[12];
    const float* w1  = (const float*)d_in[13];
    const float* b1  = (const float*)d_in[14];
    const float* w2  = (const float*)d_in[15];
    const float* b2  = (const float*)d_in[16];

    float* f = (float*)d_ws;
    float* gkq   = f; f += 448 * 64;
    float* aux   = f; f += 448 * 2;
    float* slots = f; f += 448 * 64;
    float* Ypart = f; f += (long)64 * 16 * 456;
    float* Ypar2 = f; f += (long)64 * 16 * 456;   // inert duplicate target
    float* wihT  = f; f += 64 * 192;
    float* whhT  = f; f += 64 * 192;
    float* WkT   = f; f += 64 * 64;

    init_kernel<<<112, 256, 0, stream>>>(s0, lsg, lsb, Wq, Wk, lig, lib,
                                         wih, whh, slots, gkq, aux,
                                         wihT, whhT, WkT);
    for (int it = 0; it < 3; ++it) {
        attn_kernel<<<1024, 256, 0, stream>>>(x, gkq, aux, Ypart);
        // duplicate dispatch (inert output) -- measures attn duration:
        // a = (T_R10 - T_R9) / 3
        attn_kernel<<<1024, 256, 0, stream>>>(x, gkq, aux, Ypar2);
        update_kernel<<<448, 256, 0, stream>>>(
            Ypart, slots, Wv, wihT, whhT, bih, bhh, w1, b1, w2, b2,
            lsg, lsb, Wq, WkT, lig, lib, gkq, aux,
            (float*)d_out, it == 2);
    }
}

// Round 11
// 225.637 us; speedup vs baseline: 1.2731x; 1.2731x over previous
//
#include <hip/hip_runtime.h>
#include <stdint.h>

#define L2E 1.44269504088896f

static __device__ __forceinline__ float wsum(float v) {
    #pragma unroll
    for (int m = 1; m < 64; m <<= 1) v += __shfl_xor(v, m, 64);
    return v;
}
static __device__ __forceinline__ float sigm(float x) {
    return 1.0f / (1.0f + __builtin_amdgcn_exp2f(-x * L2E));
}
static __device__ __forceinline__ float tanh_(float x) {
    const float ax = fabsf(x);
    const float t = __builtin_amdgcn_exp2f(-2.0f * ax * L2E);
    const float r = (1.0f - t) / (1.0f + t);
    return (x < 0.f) ? -r : r;
}

// DPP helper: returns neighbor's value per compile-time ctrl (VALU-rate).
template <int CTRL>
static __device__ __forceinline__ float dppterm(float v) {
    return __int_as_float(__builtin_amdgcn_update_dpp(
        0, __float_as_int(v), CTRL, 0xF, 0xF, true));
}
// Butterfly sum over 8 contiguous lanes (chunk = lane&7). All adds
// commutative -> bitwise-identical result in all 8 lanes.
static __device__ __forceinline__ float red8(float v) {
    v += dppterm<0xB1>(v);    // quad_perm(1,0,3,2)  = xor1
    v += dppterm<0x4E>(v);    // quad_perm(2,3,0,1)  = xor2
    v += dppterm<0x141>(v);   // row_half_mirror     = xor7 (quads merged)
    return v;
}

// ---------------------------------------------------------------------------
// init: fused weight transpose (wihT/whhT/WkT) + slot broadcast + iter-0
// gkq/aux. grid 112 x 256. (R1-verbatim)
// ---------------------------------------------------------------------------
__global__ __launch_bounds__(256) void init_kernel(
    const float* __restrict__ s0,
    const float* __restrict__ lsg, const float* __restrict__ lsb,
    const float* __restrict__ Wq,  const float* __restrict__ Wk,
    const float* __restrict__ lig, const float* __restrict__ lib,
    const float* __restrict__ wih, const float* __restrict__ whh,
    float* __restrict__ slots, float* __restrict__ gkq, float* __restrict__ aux,
    float* __restrict__ wihT, float* __restrict__ whhT, float* __restrict__ WkT)
{
    __shared__ float wkT[4096];
    __shared__ float scr[4][64];
    const int tid = threadIdx.x, lane = tid & 63, wv = tid >> 6;
    const int idx = blockIdx.x * 256 + tid;

    if (idx < 12288) {
        const int i = idx / 192, j = idx - i * 192;
        wihT[idx] = wih[j * 64 + i];
    } else if (idx < 24576) {
        const int o = idx - 12288;
        const int i = o / 192, j = o - i * 192;
        whhT[o] = whh[j * 64 + i];
    } else {
        const int o = idx - 24576;
        const int p = o >> 6, d = o & 63;
        WkT[o] = Wk[d * 64 + p];
    }

    const int r = blockIdx.x * 4 + wv;          // 0..447
    const int s = r % 7;
    #pragma unroll
    for (int i = tid; i < 4096; i += 256) {
        const int d = i >> 6, p = i & 63;
        wkT[p * 64 + d] = Wk[i];
    }
    const float h = s0[s * 64 + lane];
    slots[r * 64 + lane] = h;
    __syncthreads();

    const float mean = wsum(h) * (1.0f / 64.0f);
    const float d = h - mean;
    const float var = wsum(d * d) * (1.0f / 64.0f);
    const float rs = rsqrtf(var + 1e-5f);
    const float sn = d * rs * lsg[lane] + lsb[lane];
    scr[wv][lane] = sn;
    __syncthreads();
    float q = 0.f;
    #pragma unroll 8
    for (int i = 0; i < 64; ++i) q = fmaf(scr[wv][i], Wq[i * 64 + lane], q);
    q *= 0.125f;
    __syncthreads();
    scr[wv][lane] = q;
    __syncthreads();
    float kq = 0.f;
    #pragma unroll 8
    for (int p = 0; p < 64; ++p) kq = fmaf(wkT[p * 64 + lane], scr[wv][p], kq);
    const float bk = wsum(lib[lane] * kq);
    const float gk = lig[lane] * kq;
    const float g1 = wsum(gk);
    gkq[r * 64 + lane] = gk;
    if (lane == 0) { aux[r * 2] = g1; aux[r * 2 + 1] = bk; }
}

// ---------------------------------------------------------------------------
// attn v5 (R9-verbatim): async global_load_lds staging, counted vmcnt,
// double-buffered per-wave LDS tiles, R1 math. grid 1024 x 256.
// ---------------------------------------------------------------------------
#define PROC(A0, A1)                                                         \
    do {                                                                     \
        const float xv[8] = {A0.x, A0.y, A0.z, A0.w, A1.x, A1.y, A1.z, A1.w};\
        float sum = 0.f, ss = 0.f;                                           \
        _Pragma("unroll")                                                    \
        for (int j = 0; j < 8; ++j) {                                        \
            sum += xv[j]; ss = fmaf(xv[j], xv[j], ss);                       \
        }                                                                    \
        float acc[7];                                                        \
        _Pragma("unroll")                                                    \
        for (int s = 0; s < 7; ++s) {                                        \
            float a = 0.f;                                                   \
            _Pragma("unroll")                                                \
            for (int j = 0; j < 8; ++j) a = fmaf(xv[j], gk[s][j], a);        \
            acc[s] = a;                                                      \
        }                                                                    \
        sum = red8(sum);                                                     \
        ss  = red8(ss);                                                      \
        _Pragma("unroll")                                                    \
        for (int s = 0; s < 7; ++s) acc[s] = red8(acc[s]);                   \
        const float m   = sum * (1.0f / 64.0f);                              \
        const float var = ss * (1.0f / 64.0f) - m * m;                       \
        const float rs  = rsqrtf(var + 1e-5f);                               \
        const float rsm = rs * m;                                            \
        float t[7];                                                          \
        _Pragma("unroll")                                                    \
        for (int s = 0; s < 7; ++s)                                          \
            t[s] = fmaf(rs, acc[s], fmaf(-rsm, g1[s], bk[s]));               \
        float mx = t[0];                                                     \
        _Pragma("unroll")                                                    \
        for (int s = 1; s < 7; ++s) mx = fmaxf(mx, t[s]);                    \
        float e[7], se = 0.f;                                                \
        _Pragma("unroll")                                                    \
        for (int s = 0; s < 7; ++s) {                                        \
            e[s] = __builtin_amdgcn_exp2f((t[s] - mx) * L2E);                \
            se += e[s];                                                      \
        }                                                                    \
        const float inv = 1.0f / se;                                         \
        _Pragma("unroll")                                                    \
        for (int s = 0; s < 7; ++s) {                                        \
            const float w = fmaf(e[s], inv, 1e-8f);                          \
            cacc[s] += w;                                                    \
            const float wrs = w * rs;                                        \
            _Pragma("unroll")                                                \
            for (int j = 0; j < 8; ++j)                                      \
                Yacc[s][j] = fmaf(wrs, xv[j], Yacc[s][j]);                   \
        }                                                                    \
    } while (0)

#define STAGE(G, BUF)                                                        \
    do {                                                                     \
        const char* gs_ = (const char*)xw + (G) * 2048 + lane * 16;          \
        char* ls_ = (char*)&xbuf[wv][BUF][0][0];                             \
        __builtin_amdgcn_global_load_lds(                                    \
            (const __attribute__((address_space(1))) unsigned int*)gs_,      \
            (__attribute__((address_space(3))) unsigned int*)ls_, 16, 0, 0); \
        __builtin_amdgcn_global_load_lds(                                    \
            (const __attribute__((address_space(1))) unsigned int*)(gs_ + 1024), \
            (__attribute__((address_space(3))) unsigned int*)(ls_ + 1024),   \
            16, 0, 0);                                                       \
    } while (0)

#define WAITV(N)                                                             \
    do {                                                                     \
        asm volatile("s_waitcnt vmcnt(" #N ")" ::: "memory");                \
        __builtin_amdgcn_sched_barrier(0);                                   \
    } while (0)

#define PROCL(BUF)                                                           \
    do {                                                                     \
        const float4 A0_ = *(const float4*)&xbuf[wv][BUF][rsl][ck * 8];      \
        const float4 A1_ = *(const float4*)&xbuf[wv][BUF][rsl][ck * 8 + 4];  \
        PROC(A0_, A1_);                                                      \
    } while (0)

__global__ __launch_bounds__(256, 2) void attn_kernel(
    const float* __restrict__ x,
    const float* __restrict__ gkq, const float* __restrict__ aux,
    float* __restrict__ Ypart)
{
    __shared__ float ybuf[16][460];             // 29.4 KB
    __shared__ float xbuf[4][2][8][64];         // 16 KB
    const int tid = threadIdx.x, lane = tid & 63, wv = tid >> 6;
    const int b = blockIdx.x >> 4, chunk16 = blockIdx.x & 15;
    const int ck  = lane & 7;                   // dim-chunk 0..7
    const int rsl = lane >> 3;                  // row-slot 0..7

    float gk[7][8];
    {
        const float4* gp = (const float4*)(gkq + b * 448 + ck * 8);
        #pragma unroll
        for (int s = 0; s < 7; ++s) {
            const float4 u0 = gp[s * 16], u1 = gp[s * 16 + 1];
            gk[s][0] = u0.x; gk[s][1] = u0.y; gk[s][2] = u0.z; gk[s][3] = u0.w;
            gk[s][4] = u1.x; gk[s][5] = u1.y; gk[s][6] = u1.z; gk[s][7] = u1.w;
        }
    }
    const float* ab = aux + b * 14;
    float g1[7], bk[7];
    #pragma unroll
    for (int s = 0; s < 7; ++s) { g1[s] = ab[2 * s]; bk[s] = ab[2 * s + 1]; }

    float Yacc[7][8];
    #pragma unroll
    for (int s = 0; s < 7; ++s)
        #pragma unroll
        for (int j = 0; j < 8; ++j) Yacc[s][j] = 0.f;
    float cacc[7] = {0.f, 0.f, 0.f, 0.f, 0.f, 0.f, 0.f};

    const float* xw = x + (((long)b * 4096) + chunk16 * 256 + wv * 64) * 64;

    asm volatile("s_waitcnt vmcnt(0)" ::: "memory");
    __builtin_amdgcn_sched_barrier(0);

    STAGE(0, 0);
    STAGE(1, 1); WAITV(2); PROCL(0);
    STAGE(2, 0); WAITV(2); PROCL(1);
    STAGE(3, 1); WAITV(2); PROCL(0);
    STAGE(4, 0); WAITV(2); PROCL(1);
    STAGE(5, 1); WAITV(2); PROCL(0);
    STAGE(6, 0); WAITV(2); PROCL(1);
    STAGE(7, 1); WAITV(2); PROCL(0);
                 WAITV(0); PROCL(1);

    #pragma unroll
    for (int s = 0; s < 7; ++s) {
        #pragma unroll
        for (int j = 0; j < 8; ++j)
            Yacc[s][j] += dppterm<0x128>(Yacc[s][j]);
        cacc[s] += dppterm<0x128>(cacc[s]);
    }
    if (((lane >> 3) & 1) == 0) {
        const int sub = lane >> 4;              // 0..3
        float* yb = &ybuf[wv * 4 + sub][ck * 8];
        #pragma unroll
        for (int s = 0; s < 7; ++s) {
            #pragma unroll
            for (int j = 0; j < 8; ++j) yb[s * 64 + j] = Yacc[s][j];
        }
        if (ck == 0) {
            #pragma unroll
            for (int s = 0; s < 7; ++s)
                ybuf[wv * 4 + sub][448 + s] = cacc[s];
        }
    }
    __syncthreads();
    for (int i = tid; i < 455; i += 256) {
        float v = 0.f;
        #pragma unroll
        for (int p = 0; p < 16; ++p) v += ybuf[p][i];
        Ypart[((long)b * 16 + chunk16) * 456 + i] = v;
    }
}

// ---------------------------------------------------------------------------
// update v4: R5's harness-verified update64 math VERBATIM, plus bulk LDS
// weight preload. R10's split measurement: update chain ~35 us/exec because
// attn's 64 MB x-stream evicts XCD L2 -> every stage re-pulls weights from
// L3 at ~800 cyc with only 8 loads in flight. Fix: all 512 threads burst-
// copy Wv+wihT+whhT+w1 (144 KB) global->LDS before the barrier (L3 latency
// paid once, massively parallel), chains then read LDS. w2/Wq/WkT/biases
// stay global (single tail stage exposed). LDS ~153 KB -> 1 block/CU,
// grid 64 x 512.
// ---------------------------------------------------------------------------
__global__ __launch_bounds__(512) void update_kernel(
    const float* __restrict__ Ypart, float* __restrict__ slots,
    const float* __restrict__ Wv,
    const float* __restrict__ wihT, const float* __restrict__ whhT,
    const float* __restrict__ bih,  const float* __restrict__ bhh,
    const float* __restrict__ w1,   const float* __restrict__ b1,
    const float* __restrict__ w2,   const float* __restrict__ b2,
    const float* __restrict__ lsg,  const float* __restrict__ lsb,
    const float* __restrict__ Wq,   const float* __restrict__ WkT,
    const float* __restrict__ lig,  const float* __restrict__ lib,
    float* __restrict__ gkq, float* __restrict__ aux,
    float* __restrict__ out, int last)
{
    __shared__ float lWv[4096];                 // 16 KB
    __shared__ float lwih[12288];               // 48 KB
    __shared__ float lwhh[12288];               // 48 KB
    __shared__ float lw1[8192];                 // 32 KB
    __shared__ float wsYd[7][64];
    __shared__ float wsC[8];
    __shared__ float wss[7][4][64];
    const int tid = threadIdx.x, lane = tid & 63, wv = tid >> 6;
    const int b = blockIdx.x;                   // 0..63
    const float* Yb = Ypart + (long)b * 16 * 456;

    // ---- bulk weight preload: 9216 float4s over 512 threads (18/thread),
    // all issued up front -> L3 latency amortized across one deep burst ----
    {
        const float4* g0 = (const float4*)Wv;
        float4*       s0 = (float4*)lWv;
        #pragma unroll
        for (int i = 0; i < 2; ++i) s0[tid + i * 512] = g0[tid + i * 512];
        const float4* g1 = (const float4*)wihT;
        float4*       s1 = (float4*)lwih;
        #pragma unroll
        for (int i = 0; i < 6; ++i) s1[tid + i * 512] = g1[tid + i * 512];
        const float4* g2 = (const float4*)whhT;
        float4*       s2 = (float4*)lwhh;
        #pragma unroll
        for (int i = 0; i < 6; ++i) s2[tid + i * 512] = g2[tid + i * 512];
        const float4* g3 = (const float4*)w1;
        float4*       s3 = (float4*)lw1;
        #pragma unroll
        for (int i = 0; i < 4; ++i) s3[tid + i * 512] = g3[tid + i * 512];
    }

    // stage 1: Y column sums (448 lanes) + 7 colsum totals (R5-verbatim,
    // 512-thread predicate form)
    if (tid < 448) {
        float v = 0.f;
        #pragma unroll
        for (int c = 0; c < 16; ++c) v += Yb[c * 456 + tid];
        wsYd[tid >> 6][tid & 63] = v;
    } else if (tid < 455) {
        const int s = tid - 448;
        float v = 0.f;
        #pragma unroll
        for (int c = 0; c < 16; ++c) v += Yb[c * 456 + 448 + s];
        wsC[s] = v;
    }
    __syncthreads();

    if (wv < 7) {
        const int s = wv;
        const int r = b * 7 + s;
        float (*scr)[64] = wss[wv];

        const float Yd = wsYd[s][lane];
        const float C  = wsC[s];
        const float Z  = wsum(Yd) * (1.0f / 64.0f);   // Z = sum_d Y / 64
        const float a  = (lig[lane] * (Yd - Z) + lib[lane] * C) / C;
        scr[0][lane] = a;
        float u = 0.f;
        #pragma unroll 8
        for (int i = 0; i < 64; ++i) u = fmaf(scr[0][i], lWv[i * 64 + lane], u);
        const float h = slots[r * 64 + lane];
        scr[1][lane] = u;
        scr[2][lane] = h;

        float gi0 = bih[lane], gi1 = bih[64 + lane], gi2 = bih[128 + lane];
        float gh0 = bhh[lane], gh1 = bhh[64 + lane], gh2 = bhh[128 + lane];
        #pragma unroll 4
        for (int i = 0; i < 64; ++i) {
            const float ui = scr[1][i], hi = scr[2][i];
            const float* wi = &lwih[i * 192];
            const float* wh = &lwhh[i * 192];
            gi0 = fmaf(ui, wi[lane], gi0);
            gi1 = fmaf(ui, wi[64 + lane], gi1);
            gi2 = fmaf(ui, wi[128 + lane], gi2);
            gh0 = fmaf(hi, wh[lane], gh0);
            gh1 = fmaf(hi, wh[64 + lane], gh1);
            gh2 = fmaf(hi, wh[128 + lane], gh2);
        }
        const float rr = sigm(gi0 + gh0);
        const float zz = sigm(gi1 + gh1);
        const float nn = tanh_(gi2 + rr * gh2);
        const float hn = (1.f - zz) * nn + zz * h;
        scr[0][lane] = hn;

        float m0 = b1[lane], m1 = b1[64 + lane];
        #pragma unroll 8
        for (int i = 0; i < 64; ++i) {
            const float hi = scr[0][i];
            m0 = fmaf(hi, lw1[i * 128 + lane], m0);
            m1 = fmaf(hi, lw1[i * 128 + 64 + lane], m1);
        }
        scr[1][lane] = fmaxf(m0, 0.f);
        scr[2][lane] = fmaxf(m1, 0.f);

        float o2 = b2[lane];
        #pragma unroll 8
        for (int t = 0; t < 64; ++t)
            o2 = fmaf(scr[1][t], w2[t * 64 + lane], o2);
        #pragma unroll 8
        for (int t = 0; t < 64; ++t)
            o2 = fmaf(scr[2][t], w2[(64 + t) * 64 + lane], o2);
        const float snv = hn + o2;
        slots[r * 64 + lane] = snv;
        if (last) {
            out[r * 64 + lane] = snv;
        } else {
            const float mean = wsum(snv) * (1.0f / 64.0f);
            const float d = snv - mean;
            const float var = wsum(d * d) * (1.0f / 64.0f);
            const float rs = rsqrtf(var + 1e-5f);
            const float sn = d * rs * lsg[lane] + lsb[lane];
            scr[3][lane] = sn;
            float q = 0.f;
            #pragma unroll 8
            for (int i = 0; i < 64; ++i) q = fmaf(scr[3][i], Wq[i * 64 + lane], q);
            q *= 0.125f;
            scr[0][lane] = q;
            float kq = 0.f;
            #pragma unroll 8
            for (int p = 0; p < 64; ++p) kq = fmaf(WkT[p * 64 + lane], scr[0][p], kq);
            const float bk2 = wsum(lib[lane] * kq);
            const float gkv = lig[lane] * kq;
            const float g1v = wsum(gkv);
            gkq[r * 64 + lane] = gkv;
            if (lane == 0) { aux[r * 2] = g1v; aux[r * 2 + 1] = bk2; }
        }
    }
}

// ---------------------------------------------------------------------------
extern "C" void kernel_launch(void* const* d_in, const int* in_sizes, int n_in,
                              void* d_out, int out_size, void* d_ws, size_t ws_size,
                              hipStream_t stream)
{
    const float* x   = (const float*)d_in[0];
    const float* lig = (const float*)d_in[1];
    const float* lib = (const float*)d_in[2];
    const float* lsg = (const float*)d_in[3];
    const float* lsb = (const float*)d_in[4];
    const float* s0  = (const float*)d_in[5];
    const float* Wk  = (const float*)d_in[6];
    const float* Wv  = (const float*)d_in[7];
    const float* Wq  = (const float*)d_in[8];
    const float* wih = (const float*)d_in[9];
    const float* whh = (const float*)d_in[10];
    const float* bih = (const float*)d_in[11];
    const float* bhh = (const float*)d_in[12];
    const float* w1  = (const float*)d_in[13];
    const float* b1  = (const float*)d_in[14];
    const float* w2  = (const float*)d_in[15];
    const float* b2  = (const float*)d_in[16];

    float* f = (float*)d_ws;
    float* gkq   = f; f += 448 * 64;
    float* aux   = f; f += 448 * 2;
    float* slots = f; f += 448 * 64;
    float* Ypart = f; f += (long)64 * 16 * 456;
    float* wihT  = f; f += 64 * 192;
    float* whhT  = f; f += 64 * 192;
    float* WkT   = f; f += 64 * 64;

    init_kernel<<<112, 256, 0, stream>>>(s0, lsg, lsb, Wq, Wk, lig, lib,
                                         wih, whh, slots, gkq, aux,
                                         wihT, whhT, WkT);
    for (int it = 0; it < 3; ++it) {
        attn_kernel<<<1024, 256, 0, stream>>>(x, gkq, aux, Ypart);
        update_kernel<<<64, 512, 0, stream>>>(
            Ypart, slots, Wv, wihT, whhT, bih, bhh, w1, b1, w2, b2,
            lsg, lsb, Wq, WkT, lig, lib, gkq, aux,
            (float*)d_out, it == 2);
    }
}